// Round 4
// baseline (290.642 us; speedup 1.0000x reference)
//
#include <hip/hip_runtime.h>

// CELoss_Marginal_Smooth: B=4194304 rows, C=12 classes, fp32 -> scalar loss.
// R3 post-mortem: all direct-load variants plateau at ~2.5 TB/s effective.
// Cause: 48B lane stride (one row per lane) -> wave dwordx4 spans 3KB over
// 48 segments, ~3x transaction amplification vs coalesced. Fix: LDS-staged
// transpose — lane-consecutive coalesced global loads, conflict-free b128
// LDS writes/reads (row stride 12 words: quad-bank (3t+f)%8, gcd(3,8)=1).
// Reduction: plain per-block partial store + tiny second reduce kernel
// (no same-address atomic contention, no d_out memset needed).

#define CLS 12
#define ALPHA_F 0.6f
#define ROWS_PER_BLOCK 256

// att[i] = 1 / (# of 8-connected neighbors of cell i in a 3x4 grid)
__device__ __constant__ float ATT_TAB[CLS] = {
    1.0f/3.0f, 1.0f/5.0f, 1.0f/5.0f, 1.0f/3.0f,
    1.0f/5.0f, 1.0f/8.0f, 1.0f/8.0f, 1.0f/5.0f,
    1.0f/3.0f, 1.0f/5.0f, 1.0f/5.0f, 1.0f/3.0f
};

__global__ __launch_bounds__(256)
void ce_ms_partial_kernel(const float* __restrict__ outputs,
                          const int*   __restrict__ targets,
                          float* __restrict__ partial,
                          int B, float inv_b)
{
    __shared__ float tile[ROWS_PER_BLOCK * CLS];   // 12 KB, unpadded
    __shared__ float warp_part[4];

    const int t = threadIdx.x;
    const int row0 = blockIdx.x * ROWS_PER_BLOCK;        // first row of tile
    const long long f4_base = (long long)row0 * 3;       // first float4 of tile
    const long long f4_total = (long long)B * 3;

    // ---- Phase 1: fully coalesced global loads (lane-consecutive float4) ----
    const float4* gp = reinterpret_cast<const float4*>(outputs);
    float4 v0, v1, v2;
    {
        long long g0 = f4_base + t;
        long long g1 = f4_base + t + 256;
        long long g2 = f4_base + t + 512;
        v0 = (g0 < f4_total) ? gp[g0] : make_float4(0.f, 0.f, 0.f, 0.f);
        v1 = (g1 < f4_total) ? gp[g1] : make_float4(0.f, 0.f, 0.f, 0.f);
        v2 = (g2 < f4_total) ? gp[g2] : make_float4(0.f, 0.f, 0.f, 0.f);
    }
    const int my_row = row0 + t;
    const int tgt = (my_row < B) ? targets[my_row] : 0;   // coalesced

    // ---- Phase 2: LDS transpose (b128 write linear, conflict-free) ----
    float4* tp = reinterpret_cast<float4*>(tile);
    tp[t]       = v0;
    tp[t + 256] = v1;
    tp[t + 512] = v2;
    __syncthreads();

    // ---- Phase 3: each thread reads its own row (b128, conflict-free) ----
    float acc = 0.0f;
    if (my_row < B) {
        float4 f0 = tp[t * 3 + 0];
        float4 f1 = tp[t * 3 + 1];
        float4 f2 = tp[t * 3 + 2];
        float x[CLS] = { f0.x, f0.y, f0.z, f0.w,
                         f1.x, f1.y, f1.z, f1.w,
                         f2.x, f2.y, f2.z, f2.w };

        float m = x[0];
        #pragma unroll
        for (int j = 1; j < CLS; ++j) m = fmaxf(m, x[j]);

        float se = 0.0f, rs = 0.0f;
        #pragma unroll
        for (int j = 0; j < CLS; ++j) {
            se += __expf(x[j] - m);
            rs += x[j];
        }
        float lse = m + __logf(se);

        float xt = x[0];
        #pragma unroll
        for (int j = 1; j < CLS; ++j) xt = (tgt == j) ? x[j] : xt;

        float logp_t  = xt - lse;
        float row_sum = rs - (float)CLS * lse;
        float att     = ATT_TAB[tgt];

        acc = (-ALPHA_F * logp_t
               - (1.0f - ALPHA_F) * (att * (row_sum - logp_t) + logp_t)) * inv_b;
    }

    // ---- Block reduce -> one plain store per block ----
    #pragma unroll
    for (int off = 32; off > 0; off >>= 1)
        acc += __shfl_down(acc, off, 64);

    const int wave = t >> 6;
    if ((t & 63) == 0) warp_part[wave] = acc;
    __syncthreads();
    if (t == 0)
        partial[blockIdx.x] = warp_part[0] + warp_part[1] + warp_part[2] + warp_part[3];
}

__global__ __launch_bounds__(256)
void ce_ms_final_kernel(const float* __restrict__ partial, float* __restrict__ out, int n)
{
    const int t = threadIdx.x;
    float a0 = 0.f, a1 = 0.f, a2 = 0.f, a3 = 0.f;
    for (int i = t; i < n; i += 1024) {
        a0 += partial[i];
        if (i + 256 < n) a1 += partial[i + 256];
        if (i + 512 < n) a2 += partial[i + 512];
        if (i + 768 < n) a3 += partial[i + 768];
    }
    float acc = (a0 + a1) + (a2 + a3);

    #pragma unroll
    for (int off = 32; off > 0; off >>= 1)
        acc += __shfl_down(acc, off, 64);

    __shared__ float warp_part[4];
    const int wave = t >> 6;
    if ((t & 63) == 0) warp_part[wave] = acc;
    __syncthreads();
    if (t == 0)
        out[0] = warp_part[0] + warp_part[1] + warp_part[2] + warp_part[3];
}

extern "C" void kernel_launch(void* const* d_in, const int* in_sizes, int n_in,
                              void* d_out, int out_size, void* d_ws, size_t ws_size,
                              hipStream_t stream)
{
    const float* outputs = (const float*)d_in[0];
    const int*   targets = (const int*)d_in[1];
    float*       out     = (float*)d_out;
    float*       partial = (float*)d_ws;

    const int B = in_sizes[1];
    const float inv_b = 1.0f / (float)B;

    const int grid = (B + ROWS_PER_BLOCK - 1) / ROWS_PER_BLOCK;   // 16384 for B=4M
    ce_ms_partial_kernel<<<grid, 256, 0, stream>>>(outputs, targets, partial, B, inv_b);
    ce_ms_final_kernel<<<1, 256, 0, stream>>>(partial, out, grid);
}

// Round 6
// 266.259 us; speedup vs baseline: 1.0916x; 1.0916x over previous
//
#include <hip/hip_runtime.h>

// CELoss_Marginal_Smooth: B=4194304 rows, C=12 classes, fp32 -> scalar loss.
// R4 post-mortem: strided-register (R3), strided-loop (R2) and coalesced
// LDS-transpose (R4) ALL tie at ~90us inferred -> access pattern is NOT the
// limiter. Shared trait: loads in flight only briefly per wave (front-loaded
// loads, then compute + barriers + block churn with an empty VMEM pipe) ->
// ~35% memory duty cycle = 95us. Fix: persistent waves, wave-private LDS
// slices (NO barriers in loop), register double-buffered tiles so >=4 loads
// stay in flight continuously; nontemporal loads (single-pass data).
// R5 fix: __builtin_nontemporal_load needs a NATIVE vector type, not HIP's
// float4 class -> use ext_vector_type(4) float alias.

#define CLS 12
#define ALPHA_F 0.6f
#define ROWS_PER_TILE 256
#define TILES 8
#define ROWS_PER_BLOCK (ROWS_PER_TILE * TILES)   // 2048

typedef float floatx4 __attribute__((ext_vector_type(4)));

// att[i] = 1 / (# of 8-connected neighbors of cell i in a 3x4 grid)
__device__ __constant__ float ATT_TAB[CLS] = {
    1.0f/3.0f, 1.0f/5.0f, 1.0f/5.0f, 1.0f/3.0f,
    1.0f/5.0f, 1.0f/8.0f, 1.0f/8.0f, 1.0f/5.0f,
    1.0f/3.0f, 1.0f/5.0f, 1.0f/5.0f, 1.0f/3.0f
};

__device__ __forceinline__ float row_loss_compute(floatx4 f0, floatx4 f1, floatx4 f2, int t)
{
    float x[CLS] = { f0.x, f0.y, f0.z, f0.w,
                     f1.x, f1.y, f1.z, f1.w,
                     f2.x, f2.y, f2.z, f2.w };

    float m = x[0];
    #pragma unroll
    for (int j = 1; j < CLS; ++j) m = fmaxf(m, x[j]);

    float se = 0.0f, rs = 0.0f;
    #pragma unroll
    for (int j = 0; j < CLS; ++j) {
        se += __expf(x[j] - m);
        rs += x[j];
    }
    float lse = m + __logf(se);

    float xt = x[0];
    #pragma unroll
    for (int j = 1; j < CLS; ++j) xt = (t == j) ? x[j] : xt;

    float logp_t  = xt - lse;
    float row_sum = rs - (float)CLS * lse;
    float att     = ATT_TAB[t];

    return -ALPHA_F * logp_t
           - (1.0f - ALPHA_F) * (att * (row_sum - logp_t) + logp_t);
}

__global__ __launch_bounds__(256)
void ce_ms_partial_kernel(const float* __restrict__ outputs,
                          const int*   __restrict__ targets,
                          float* __restrict__ partial,
                          int B, float inv_b)
{
    __shared__ float tile[256 * CLS];        // 12 KB: four wave-private 3 KB slices
    __shared__ float warp_part[4];

    const int t    = threadIdx.x;
    const int lane = t & 63;
    const int wave = t >> 6;
    floatx4* ws4 = reinterpret_cast<floatx4*>(tile) + wave * 192;  // 192 float4 per wave

    const floatx4* gp = reinterpret_cast<const floatx4*>(outputs);
    float acc = 0.0f;

    const long long blk_row0 = (long long)blockIdx.x * ROWS_PER_BLOCK;

    if (blk_row0 + ROWS_PER_BLOCK <= (long long)B) {
        // Fast path: this wave owns rows [wrow + k*256, +64) for k=0..7.
        const long long wrow = blk_row0 + wave * 64;

        // Prefetch tile 0 (coalesced, lane-consecutive float4).
        long long fb = wrow * 3;
        floatx4 n0 = __builtin_nontemporal_load(gp + fb + lane);
        floatx4 n1 = __builtin_nontemporal_load(gp + fb + 64 + lane);
        floatx4 n2 = __builtin_nontemporal_load(gp + fb + 128 + lane);
        int     nt = __builtin_nontemporal_load(targets + wrow + lane);

        #pragma unroll
        for (int k = 0; k < TILES; ++k) {
            floatx4 c0 = n0, c1 = n1, c2 = n2;
            int     ct = nt;
            if (k + 1 < TILES) {
                // Issue next tile's loads BEFORE consuming this tile ->
                // VMEM pipe never drains (compiler emits partial vmcnt waits).
                long long r2  = wrow + (long long)(k + 1) * ROWS_PER_TILE;
                long long f2b = r2 * 3;
                n0 = __builtin_nontemporal_load(gp + f2b + lane);
                n1 = __builtin_nontemporal_load(gp + f2b + 64 + lane);
                n2 = __builtin_nontemporal_load(gp + f2b + 128 + lane);
                nt = __builtin_nontemporal_load(targets + r2 + lane);
            }
            // Wave-private LDS transpose: no __syncthreads needed (intra-wave
            // DS ops are ordered; slices are disjoint across waves).
            ws4[lane]       = c0;
            ws4[lane + 64]  = c1;
            ws4[lane + 128] = c2;
            floatx4 f0  = ws4[lane * 3 + 0];
            floatx4 f1  = ws4[lane * 3 + 1];
            floatx4 f2v = ws4[lane * 3 + 2];
            acc += row_loss_compute(f0, f1, f2v, ct);
        }
    } else {
        // Tail path (unused when ROWS_PER_BLOCK divides B): direct strided loads.
        for (int k = 0; k < TILES; ++k) {
            long long row = blk_row0 + (long long)k * ROWS_PER_TILE + t;
            if (row < (long long)B) {
                const floatx4* p = gp + row * 3;
                acc += row_loss_compute(p[0], p[1], p[2], targets[row]);
            }
        }
    }

    acc *= inv_b;

    // wave64 butterfly reduce
    #pragma unroll
    for (int off = 32; off > 0; off >>= 1)
        acc += __shfl_down(acc, off, 64);

    if ((t & 63) == 0) warp_part[wave] = acc;
    __syncthreads();
    if (t == 0)
        partial[blockIdx.x] = warp_part[0] + warp_part[1] + warp_part[2] + warp_part[3];
}

__global__ __launch_bounds__(256)
void ce_ms_final_kernel(const float* __restrict__ partial, float* __restrict__ out, int n)
{
    const int t = threadIdx.x;
    float acc = 0.0f;
    for (int i = t; i < n; i += 256)
        acc += partial[i];

    #pragma unroll
    for (int off = 32; off > 0; off >>= 1)
        acc += __shfl_down(acc, off, 64);

    __shared__ float warp_part[4];
    const int wave = t >> 6;
    if ((t & 63) == 0) warp_part[wave] = acc;
    __syncthreads();
    if (t == 0)
        out[0] = warp_part[0] + warp_part[1] + warp_part[2] + warp_part[3];
}

extern "C" void kernel_launch(void* const* d_in, const int* in_sizes, int n_in,
                              void* d_out, int out_size, void* d_ws, size_t ws_size,
                              hipStream_t stream)
{
    const float* outputs = (const float*)d_in[0];
    const int*   targets = (const int*)d_in[1];
    float*       out     = (float*)d_out;
    float*       partial = (float*)d_ws;

    const int B = in_sizes[1];
    const float inv_b = 1.0f / (float)B;

    const int grid = (int)(((long long)B + ROWS_PER_BLOCK - 1) / ROWS_PER_BLOCK);  // 2048
    ce_ms_partial_kernel<<<grid, 256, 0, stream>>>(outputs, targets, partial, B, inv_b);
    ce_ms_final_kernel<<<1, 256, 0, stream>>>(partial, out, grid);
}